// Round 4
// baseline (606.184 us; speedup 1.0000x reference)
//
#include <hip/hip_runtime.h>

// GraphReasonLayer: out = relu( (softmax(QK^T) @ inp) @ Wo + bo ),
//   Q = inp@Wq+bq, K = inp@Wk+bk.  B=16, N=2048, D=256, fp32 in/out.
// R4: Wo folded into V (V' = inp@Wo; out = relu((P@V')/l + bo) — exact
// rearrangement). Attn: 32q/wave (2 x 16q tiles), exp(s-32) softmax with no
// max/rescale (O = pure MFMA sink), K+V prefetched into registers then
// staged to LDS (hides L2 latency — R3's poison was serialized global V).
// launch_bounds(128,1): 512-reg cap, no spill (R2's poison was the reg cap).

#define DEVI __device__ __forceinline__

using f16x8  = __attribute__((ext_vector_type(8))) _Float16;
using bs16x8 = __attribute__((ext_vector_type(8))) short;  // bf16 bits
using f32x4  = __attribute__((ext_vector_type(4))) float;
using u16x4  = __attribute__((ext_vector_type(4))) unsigned short;
using u16x8  = __attribute__((ext_vector_type(8))) unsigned short;

constexpr int Bn = 16, Nn = 2048, Dn = 256;
constexpr float Coff = 32.0f;  // fixed softmax offset; cancels in O/l

DEVI unsigned short f2h(float x) {
  return __builtin_bit_cast(unsigned short, (_Float16)x);
}
DEVI float h2f(unsigned short h) {
  return (float)__builtin_bit_cast(_Float16, h);
}
DEVI unsigned short f2bf(float x) {  // RNE float->bf16
  union { float f; unsigned u; } v; v.f = x;
  unsigned r = v.u + 0x7fff + ((v.u >> 16) & 1);
  return (unsigned short)(r >> 16);
}

// ---------------------------------------------------------------- prep_w
// WT[mat][n][k] = W[k][n] as fp16 (0=Wq, 1=Wk, 2=Wo).
__global__ __launch_bounds__(256) void prep_w(
    const float* __restrict__ Wq, const float* __restrict__ Wk,
    const float* __restrict__ Wo, unsigned short* __restrict__ WT) {
  const int mat = blockIdx.x >> 8, n = blockIdx.x & 255, k = threadIdx.x;
  const float* src = mat == 0 ? Wq : (mat == 1 ? Wk : Wo);
  WT[(size_t)mat * 65536 + n * 256 + k] = f2h(src[k * 256 + n]);
}

// ---------------------------------------------------------------- GEMM
// {Qf,Kf,Vp}[b][n][d] = inp @ {Wq,Wk,Wo} (+bias for q,k), fp16 out.
// Block 64 rows x 256 cols, 4 waves; blockIdx.y = which weight.
__global__ __launch_bounds__(256, 4) void gemm_kernel(
    const float* __restrict__ A, const unsigned short* __restrict__ WTbase,
    const float* __restrict__ bq, const float* __restrict__ bk,
    unsigned short* __restrict__ Qf, unsigned short* __restrict__ Kf,
    unsigned short* __restrict__ Vp) {
  __shared__ __align__(16) unsigned short sA[64 * 40];
  __shared__ __align__(16) unsigned short sW[256 * 40];
  const int t = threadIdx.x, w = t >> 6, l = t & 63;
  const int lq = l & 15, quad = l >> 4;
  const int m0 = blockIdx.x * 64, s = blockIdx.y;
  const unsigned short* WT = WTbase + (size_t)s * 65536;
  const float* bias = s == 0 ? bq : (s == 1 ? bk : nullptr);
  unsigned short* outH = s == 0 ? Qf : (s == 1 ? Kf : Vp);

  f32x4 acc[16];
#pragma unroll
  for (int c = 0; c < 16; c++) acc[c] = f32x4{0.f, 0.f, 0.f, 0.f};

  for (int kc = 0; kc < 8; kc++) {
    __syncthreads();
    {  // stage A 64x32 fp32->fp16
      int r = t >> 2, k8 = (t & 3) * 8;
      const float* Ap = A + (size_t)(m0 + r) * Dn + kc * 32 + k8;
      float4 v0 = *(const float4*)Ap, v1 = *(const float4*)(Ap + 4);
      u16x8 h;
      h[0] = f2h(v0.x); h[1] = f2h(v0.y); h[2] = f2h(v0.z); h[3] = f2h(v0.w);
      h[4] = f2h(v1.x); h[5] = f2h(v1.y); h[6] = f2h(v1.z); h[7] = f2h(v1.w);
      *(u16x8*)&sA[r * 40 + k8] = h;
    }
#pragma unroll
    for (int j = 0; j < 4; j++) {  // stage W chunk [256 n][32 k]
      int idx = j * 256 + t, n = idx >> 2, k8 = (idx & 3) * 8;
      *(uint4*)&sW[n * 40 + k8] = *(const uint4*)(WT + (size_t)n * 256 + kc * 32 + k8);
    }
    __syncthreads();
    f16x8 a = *(const f16x8*)&sA[(w * 16 + lq) * 40 + quad * 8];
#pragma unroll
    for (int c = 0; c < 16; c++) {
      f16x8 bf = *(const f16x8*)&sW[(c * 16 + lq) * 40 + quad * 8];
      acc[c] = __builtin_amdgcn_mfma_f32_16x16x32_f16(a, bf, acc[c], 0, 0, 0);
    }
  }
  const int row_l = w * 16 + quad * 4;
#pragma unroll
  for (int c = 0; c < 16; c++) {
    int col = c * 16 + lq;
    float bs = bias ? bias[col] : 0.f;
#pragma unroll
    for (int r = 0; r < 4; r++)
      outH[(size_t)(m0 + row_l + r) * Dn + col] = f2h(acc[c][r] + bs);
  }
}

// ---------------------------------------------------------------- transpose
// Vp [B][N][D] fp16 -> VT [B][D][N] bf16
__global__ __launch_bounds__(256) void transpose_h(
    const unsigned short* __restrict__ Vp, unsigned short* __restrict__ VT) {
  __shared__ float sT[64][65];
  const int b = blockIdx.z, n0 = blockIdx.x * 64, d0 = blockIdx.y * 64;
  const int t = threadIdx.x;
  const unsigned short* src = Vp + ((size_t)b * Nn + n0) * Dn + d0;
#pragma unroll
  for (int i = 0; i < 4; i++) {
    int g = t + i * 256, r = g >> 4, c4 = (g & 15) * 4;
    u16x4 h = *(const u16x4*)(src + (size_t)r * Dn + c4);
#pragma unroll
    for (int j = 0; j < 4; j++) sT[r][c4 + j] = h2f(h[j]);
  }
  __syncthreads();
  unsigned short* dst = VT + ((size_t)b * Dn + d0) * Nn + n0;
#pragma unroll
  for (int i = 0; i < 4; i++) {
    int g = t + i * 256, r = g >> 4, c4 = (g & 15) * 4;
    u16x4 o;
#pragma unroll
    for (int j = 0; j < 4; j++) o[j] = f2bf(sT[c4 + j][r]);
    *(u16x4*)(dst + (size_t)r * Nn + c4) = o;
  }
}

// ---------------------------------------------------------------- attention
// Block = 128 thr = 2 waves, each wave 32 q (2 tiles of 16). Grid 512.
// Per 32-key chunk: stage K(16KB)+V'(16KB) via register prefetch, scores
// fp16 MFMA, P=exp(s-32) bf16, O += P@V' (bf16 MFMA), l via ones-MFMA.
// Epilogue: out = relu(O/l + bo) fp32, written straight to d_out.
__global__ __launch_bounds__(128, 1) void attn_kernel(
    const unsigned short* __restrict__ Qf, const unsigned short* __restrict__ Kf,
    const unsigned short* __restrict__ VT, const float* __restrict__ bo,
    float* __restrict__ out) {
  __shared__ __align__(16) unsigned short sK[32 * 264];   // [key][k] 16896 B
  __shared__ __align__(16) unsigned short sV[256 * 40];   // [d][key] 20480 B
  __shared__ __align__(16) unsigned short sP[2][32 * 40]; // per-wave P
  const int t = threadIdx.x, w = t >> 6, l = t & 63;
  const int lq = l & 15, quad = l >> 4;
  // XCD-affine: 512 blocks; batches b, b+8 pinned to XCD (id&7)
  const int id = blockIdx.x, xcd = id & 7, r2 = id >> 3;
  const int b = xcd | ((r2 & 1) << 3), n0 = (r2 >> 1) * 64;
  unsigned short* sPw = sP[w];

  // Q fragments: 2 q-tiles x 8 k-steps (A-layout m=lq, k=quad*8+j)
  f16x8 qfrag[2][8];
#pragma unroll
  for (int qt = 0; qt < 2; qt++) {
    const unsigned short* qp =
        Qf + ((size_t)b * Nn + n0 + w * 32 + qt * 16 + lq) * Dn + quad * 8;
#pragma unroll
    for (int s = 0; s < 8; s++) qfrag[qt][s] = *(const f16x8*)(qp + s * 32);
  }
  float bo_r[16];
#pragma unroll
  for (int c = 0; c < 16; c++) bo_r[c] = bo[c * 16 + lq];
  bs16x8 onesb;
#pragma unroll
  for (int i = 0; i < 8; i++) onesb[i] = (short)0x3F80;  // bf16 1.0

  f32x4 O[2][17];  // [qtile][16 d-tiles + l]; pure MFMA sinks
#pragma unroll
  for (int qt = 0; qt < 2; qt++)
#pragma unroll
    for (int c = 0; c < 17; c++) O[qt][c] = f32x4{0.f, 0.f, 0.f, 0.f};

  const unsigned short* kg = Kf + (size_t)b * Nn * Dn;
  const unsigned short* vg = VT + (size_t)b * Dn * Nn;

  // register prefetch: K = 1024 uint4, V = 1024 uint4; 16 per thread
  uint4 pre[16];
#pragma unroll
  for (int j = 0; j < 8; j++)
    pre[j] = ((const uint4*)kg)[j * 128 + t];
#pragma unroll
  for (int j = 0; j < 8; j++) {
    int i = j * 128 + t, d = i >> 2, c4 = i & 3;
    pre[8 + j] = *(const uint4*)(vg + (size_t)d * Nn + c4 * 8);
  }

  for (int mc = 0; mc < 64; mc++) {
    __syncthreads();  // prev-iteration readers done
    // commit staged chunk to LDS
#pragma unroll
    for (int j = 0; j < 8; j++) {
      int i = j * 128 + t;
      *(uint4*)&sK[(i >> 5) * 264 + (i & 31) * 8] = pre[j];
    }
#pragma unroll
    for (int j = 0; j < 8; j++) {
      int i = j * 128 + t, d = i >> 2, c4 = i & 3;
      *(uint4*)&sV[d * 40 + c4 * 8] = pre[8 + j];
    }
    // issue next chunk's loads (latency hidden behind compute below)
    if (mc + 1 < 64) {
      const int m1 = (mc + 1) * 32;
      const uint4* kgc = (const uint4*)(kg + (size_t)m1 * Dn);
#pragma unroll
      for (int j = 0; j < 8; j++) pre[j] = kgc[j * 128 + t];
#pragma unroll
      for (int j = 0; j < 8; j++) {
        int i = j * 128 + t, d = i >> 2, c4 = i & 3;
        pre[8 + j] = *(const uint4*)(vg + (size_t)d * Nn + m1 + c4 * 8);
      }
    }
    __syncthreads();
    // scores: 32 q x 32 keys; each kf feeds 2 MFMAs
    f32x4 st[2][2];
#pragma unroll
    for (int qt = 0; qt < 2; qt++)
#pragma unroll
      for (int tt = 0; tt < 2; tt++) st[qt][tt] = f32x4{0.f, 0.f, 0.f, 0.f};
#pragma unroll
    for (int s = 0; s < 8; s++) {
#pragma unroll
      for (int tt = 0; tt < 2; tt++) {
        f16x8 kf = *(const f16x8*)&sK[(tt * 16 + lq) * 264 + s * 32 + quad * 8];
        st[0][tt] = __builtin_amdgcn_mfma_f32_16x16x32_f16(qfrag[0][s], kf, st[0][tt], 0, 0, 0);
        st[1][tt] = __builtin_amdgcn_mfma_f32_16x16x32_f16(qfrag[1][s], kf, st[1][tt], 0, 0, 0);
      }
    }
    // P = exp(s - 32) -> bf16 (no max, no rescale)
#pragma unroll
    for (int qt = 0; qt < 2; qt++)
#pragma unroll
      for (int tt = 0; tt < 2; tt++)
#pragma unroll
        for (int r = 0; r < 4; r++) {
          float p = __expf(st[qt][tt][r] - Coff);
          sPw[(qt * 16 + quad * 4 + r) * 40 + tt * 16 + lq] = f2bf(p);
        }
    // O += P @ V' ; each vf feeds 2 MFMAs; ones-column -> l (all cols = l)
    bs16x8 pf0 = *(const bs16x8*)&sPw[lq * 40 + quad * 8];
    bs16x8 pf1 = *(const bs16x8*)&sPw[(16 + lq) * 40 + quad * 8];
#pragma unroll
    for (int c = 0; c < 16; c++) {
      bs16x8 vf = *(const bs16x8*)&sV[(c * 16 + lq) * 40 + quad * 8];
      O[0][c] = __builtin_amdgcn_mfma_f32_16x16x32_bf16(pf0, vf, O[0][c], 0, 0, 0);
      O[1][c] = __builtin_amdgcn_mfma_f32_16x16x32_bf16(pf1, vf, O[1][c], 0, 0, 0);
    }
    O[0][16] = __builtin_amdgcn_mfma_f32_16x16x32_bf16(pf0, onesb, O[0][16], 0, 0, 0);
    O[1][16] = __builtin_amdgcn_mfma_f32_16x16x32_bf16(pf1, onesb, O[1][16], 0, 0, 0);
  }
  // epilogue: out = relu(O/l + bo), fp32
#pragma unroll
  for (int qt = 0; qt < 2; qt++) {
    float inv[4];
#pragma unroll
    for (int r = 0; r < 4; r++) inv[r] = 1.f / O[qt][16][r];
    const size_t base = ((size_t)b * Nn + n0 + w * 32 + qt * 16 + quad * 4) * Dn;
#pragma unroll
    for (int c = 0; c < 16; c++) {
      int col = c * 16 + lq;
#pragma unroll
      for (int r = 0; r < 4; r++) {
        float v = O[qt][c][r] * inv[r] + bo_r[c];
        out[base + (size_t)r * Dn + col] = v > 0.f ? v : 0.f;
      }
    }
  }
}

// ---------------------------------------------------------------- launch
extern "C" void kernel_launch(void* const* d_in, const int* in_sizes, int n_in,
                              void* d_out, int out_size, void* d_ws, size_t ws_size,
                              hipStream_t stream) {
  const float* inp = (const float*)d_in[0];
  const float* Wq  = (const float*)d_in[1];
  const float* bq  = (const float*)d_in[2];
  const float* Wk  = (const float*)d_in[3];
  const float* bk  = (const float*)d_in[4];
  const float* Wo  = (const float*)d_in[5];
  const float* bo  = (const float*)d_in[6];

  unsigned short* ws16 = (unsigned short*)d_ws;
  const size_t SZH = (size_t)Bn * Nn * Dn;  // 8.39M halves (16.8 MB)
  unsigned short* Qf = ws16;                // fp16 [b][n][d]
  unsigned short* Kf = ws16 + SZH;          // fp16 [b][n][d]
  unsigned short* Vp = ws16 + 2 * SZH;      // fp16 [b][n][d]  (inp@Wo)
  unsigned short* VT = ws16 + 3 * SZH;      // bf16 [b][d][n]
  unsigned short* WT = ws16 + 4 * SZH;      // 3 x 65536 fp16

  prep_w<<<768, 256, 0, stream>>>(Wq, Wk, Wo, WT);
  gemm_kernel<<<dim3(512, 3), 256, 0, stream>>>(inp, WT, bq, bk, Qf, Kf, Vp);
  transpose_h<<<dim3(32, 4, 16), 256, 0, stream>>>(Vp, VT);
  attn_kernel<<<512, 128, 0, stream>>>(Qf, Kf, VT, bo, (float*)d_out);
}

// Round 5
// 256.649 us; speedup vs baseline: 2.3619x; 2.3619x over previous
//
#include <hip/hip_runtime.h>

// GraphReasonLayer: out = relu( (softmax(QK^T) @ inp) @ Wo + bo ),
//   Q = inp@Wq+bq, K = inp@Wk+bk.  B=16, N=2048, D=256, fp32 in/out.
// R5: R4 compute core (exp(s-32) no-rescale softmax, Wo folded into V,
// 32q/wave) with staging rebuilt: global_load_lds width=16 (zero VGPRs —
// R4's poison was the spilled register-prefetch: 508 MB scratch writes),
// double-buffered LDS (1 barrier/iter), XOR-swizzled global source
// addresses so LDS stays lane-contiguous yet frag reads are 2-way (free).

#define DEVI __device__ __forceinline__

using f16x8  = __attribute__((ext_vector_type(8))) _Float16;
using bs16x8 = __attribute__((ext_vector_type(8))) short;  // bf16 bits
using f32x4  = __attribute__((ext_vector_type(4))) float;
using u16x4  = __attribute__((ext_vector_type(4))) unsigned short;
using u16x8  = __attribute__((ext_vector_type(8))) unsigned short;

constexpr int Bn = 16, Nn = 2048, Dn = 256;
constexpr float Coff = 32.0f;  // fixed softmax offset; cancels in O/l

DEVI unsigned short f2h(float x) {
  return __builtin_bit_cast(unsigned short, (_Float16)x);
}
DEVI float h2f(unsigned short h) {
  return (float)__builtin_bit_cast(_Float16, h);
}
DEVI unsigned short f2bf(float x) {  // RNE float->bf16
  union { float f; unsigned u; } v; v.f = x;
  unsigned r = v.u + 0x7fff + ((v.u >> 16) & 1);
  return (unsigned short)(r >> 16);
}

// async global->LDS, 16B per lane; LDS dest = wave-uniform base + lane*16
DEVI void gll16(const void* g, void* l) {
  __builtin_amdgcn_global_load_lds(
      (const __attribute__((address_space(1))) unsigned int*)g,
      (__attribute__((address_space(3))) unsigned int*)l, 16, 0, 0);
}

// ---------------------------------------------------------------- prep_w
// WT[mat][n][k] = W[k][n] as fp16 (0=Wq, 1=Wk, 2=Wo).
__global__ __launch_bounds__(256) void prep_w(
    const float* __restrict__ Wq, const float* __restrict__ Wk,
    const float* __restrict__ Wo, unsigned short* __restrict__ WT) {
  const int mat = blockIdx.x >> 8, n = blockIdx.x & 255, k = threadIdx.x;
  const float* src = mat == 0 ? Wq : (mat == 1 ? Wk : Wo);
  WT[(size_t)mat * 65536 + n * 256 + k] = f2h(src[k * 256 + n]);
}

// ---------------------------------------------------------------- GEMM
// {Qf,Kf,Vp}[b][n][d] = inp @ {Wq,Wk,Wo} (+bias for q,k), fp16 out.
// Block 64 rows x 256 cols, 4 waves; blockIdx.y = which weight.
__global__ __launch_bounds__(256, 4) void gemm_kernel(
    const float* __restrict__ A, const unsigned short* __restrict__ WTbase,
    const float* __restrict__ bq, const float* __restrict__ bk,
    unsigned short* __restrict__ Qf, unsigned short* __restrict__ Kf,
    unsigned short* __restrict__ Vp) {
  __shared__ __align__(16) unsigned short sA[64 * 40];
  __shared__ __align__(16) unsigned short sW[256 * 40];
  const int t = threadIdx.x, w = t >> 6, l = t & 63;
  const int lq = l & 15, quad = l >> 4;
  const int m0 = blockIdx.x * 64, s = blockIdx.y;
  const unsigned short* WT = WTbase + (size_t)s * 65536;
  const float* bias = s == 0 ? bq : (s == 1 ? bk : nullptr);
  unsigned short* outH = s == 0 ? Qf : (s == 1 ? Kf : Vp);

  f32x4 acc[16];
#pragma unroll
  for (int c = 0; c < 16; c++) acc[c] = f32x4{0.f, 0.f, 0.f, 0.f};

  for (int kc = 0; kc < 8; kc++) {
    __syncthreads();
    {  // stage A 64x32 fp32->fp16
      int r = t >> 2, k8 = (t & 3) * 8;
      const float* Ap = A + (size_t)(m0 + r) * Dn + kc * 32 + k8;
      float4 v0 = *(const float4*)Ap, v1 = *(const float4*)(Ap + 4);
      u16x8 h;
      h[0] = f2h(v0.x); h[1] = f2h(v0.y); h[2] = f2h(v0.z); h[3] = f2h(v0.w);
      h[4] = f2h(v1.x); h[5] = f2h(v1.y); h[6] = f2h(v1.z); h[7] = f2h(v1.w);
      *(u16x8*)&sA[r * 40 + k8] = h;
    }
#pragma unroll
    for (int j = 0; j < 4; j++) {  // stage W chunk [256 n][32 k]
      int idx = j * 256 + t, n = idx >> 2, k8 = (idx & 3) * 8;
      *(uint4*)&sW[n * 40 + k8] = *(const uint4*)(WT + (size_t)n * 256 + kc * 32 + k8);
    }
    __syncthreads();
    f16x8 a = *(const f16x8*)&sA[(w * 16 + lq) * 40 + quad * 8];
#pragma unroll
    for (int c = 0; c < 16; c++) {
      f16x8 bf = *(const f16x8*)&sW[(c * 16 + lq) * 40 + quad * 8];
      acc[c] = __builtin_amdgcn_mfma_f32_16x16x32_f16(a, bf, acc[c], 0, 0, 0);
    }
  }
  const int row_l = w * 16 + quad * 4;
#pragma unroll
  for (int c = 0; c < 16; c++) {
    int col = c * 16 + lq;
    float bs = bias ? bias[col] : 0.f;
#pragma unroll
    for (int r = 0; r < 4; r++)
      outH[(size_t)(m0 + row_l + r) * Dn + col] = f2h(acc[c][r] + bs);
  }
}

// ---------------------------------------------------------------- transpose
// Vp [B][N][D] fp16 -> VT [B][D][N] bf16
__global__ __launch_bounds__(256) void transpose_h(
    const unsigned short* __restrict__ Vp, unsigned short* __restrict__ VT) {
  __shared__ float sT[64][65];
  const int b = blockIdx.z, n0 = blockIdx.x * 64, d0 = blockIdx.y * 64;
  const int t = threadIdx.x;
  const unsigned short* src = Vp + ((size_t)b * Nn + n0) * Dn + d0;
#pragma unroll
  for (int i = 0; i < 4; i++) {
    int g = t + i * 256, r = g >> 4, c4 = (g & 15) * 4;
    u16x4 h = *(const u16x4*)(src + (size_t)r * Dn + c4);
#pragma unroll
    for (int j = 0; j < 4; j++) sT[r][c4 + j] = h2f(h[j]);
  }
  __syncthreads();
  unsigned short* dst = VT + ((size_t)b * Dn + d0) * Nn + n0;
#pragma unroll
  for (int i = 0; i < 4; i++) {
    int g = t + i * 256, r = g >> 4, c4 = (g & 15) * 4;
    u16x4 o;
#pragma unroll
    for (int j = 0; j < 4; j++) o[j] = f2bf(sT[c4 + j][r]);
    *(u16x4*)(dst + (size_t)r * Nn + c4) = o;
  }
}

// ---------------------------------------------------------------- attention
// 256 thr = 4 waves x 32 q (2 tiles of 16) = 128 q/block; grid 256 (1/CU).
// Per 32-key chunk: K(16KB)+V'(16KB) staged via global_load_lds into the
// double buffer; scores fp16 MFMA; P = exp(s-32) bf16 via per-wave sP;
// O += P@V' (bf16 MFMA); l via ones-column MFMA; no max, no rescale.
// LDS layouts are lane-contiguous 16B chunks with XOR swizzle applied on
// the GLOBAL source side:  K phys chunk = key*32 + (c ^ (key&7)),
// V phys chunk = d*4 + (c ^ ((d>>1)&3))  -> frag reads 2-way (free).
__global__ __launch_bounds__(256, 1) void attn_kernel(
    const unsigned short* __restrict__ Qf, const unsigned short* __restrict__ Kf,
    const unsigned short* __restrict__ VT, const float* __restrict__ bo,
    float* __restrict__ out) {
  __shared__ __align__(16) unsigned short sK[2][8192];  // 2 x 16 KB
  __shared__ __align__(16) unsigned short sV[2][8192];  // 2 x 16 KB
  __shared__ __align__(16) unsigned short sP[4][1280];  // per-wave, 32 x 40
  const int t = threadIdx.x, w = t >> 6, l = t & 63;
  const int lq = l & 15, quad = l >> 4;
  // XCD-affine: 256 blocks; batches b, b+8 pinned to XCD (id&7)
  const int id = blockIdx.x, xcd = id & 7, r2 = id >> 3;
  const int b = xcd | ((r2 & 1) << 3), n0 = (r2 >> 1) * 128;
  unsigned short* sPw = sP[w];

  const unsigned short* kg = Kf + (size_t)b * Nn * Dn;
  const unsigned short* vg = VT + (size_t)b * Dn * Nn;

  // Q fragments: 2 q-tiles x 8 k-steps (A-layout m=lq, k=quad*8+j)
  f16x8 qfrag[2][8];
#pragma unroll
  for (int qt = 0; qt < 2; qt++) {
    const unsigned short* qp =
        Qf + ((size_t)b * Nn + n0 + w * 32 + qt * 16 + lq) * Dn + quad * 8;
#pragma unroll
    for (int s = 0; s < 8; s++) qfrag[qt][s] = *(const f16x8*)(qp + s * 32);
  }
  float bo_r[16];
#pragma unroll
  for (int c = 0; c < 16; c++) bo_r[c] = bo[c * 16 + lq];
  bs16x8 onesb;
#pragma unroll
  for (int i = 0; i < 8; i++) onesb[i] = (short)0x3F80;  // bf16 1.0

  f32x4 O[2][17];  // [qtile][16 d-tiles + l]; pure MFMA sinks
#pragma unroll
  for (int qt = 0; qt < 2; qt++)
#pragma unroll
    for (int c = 0; c < 17; c++) O[qt][c] = f32x4{0.f, 0.f, 0.f, 0.f};

  // ---- async stage of one 32-key chunk into buffer buf (8 gll16 / thread)
  auto stage = [&](int buf, int m0) {
#pragma unroll
    for (int j = 0; j < 4; j++) {           // K: 4 instrs/wave x 1024 B
      int g = w * 4 + j;                    // wave-uniform instr index
      int phys = g * 64 + l;                // chunk 0..1023
      int key = phys >> 5;
      int c = (phys & 31) ^ (key & 7);
      gll16(kg + (size_t)(m0 + key) * Dn + c * 8, &sK[buf][g * 512]);
    }
#pragma unroll
    for (int j = 0; j < 4; j++) {           // V: 4 instrs/wave x 1024 B
      int g = w * 4 + j;
      int phys = g * 64 + l;
      int d = phys >> 2;
      int c = (phys & 3) ^ ((d >> 1) & 3);
      gll16(vg + (size_t)d * Nn + m0 + c * 8, &sV[buf][g * 512]);
    }
  };

  stage(0, 0);  // prologue: chunk 0 in flight

  for (int mc = 0; mc < 64; mc++) {
    const int buf = mc & 1;
    __syncthreads();  // drains vmcnt -> buf ready; all waves done with buf^1
    if (mc < 63) stage(buf ^ 1, (mc + 1) * 32);  // overlap next chunk
    const unsigned short* sKb = sK[buf];
    const unsigned short* sVb = sV[buf];

    // scores: 32 q x 32 keys; each kf feeds 2 MFMAs
    f32x4 st[2][2];
#pragma unroll
    for (int qt = 0; qt < 2; qt++)
#pragma unroll
      for (int tt = 0; tt < 2; tt++) st[qt][tt] = f32x4{0.f, 0.f, 0.f, 0.f};
#pragma unroll
    for (int s = 0; s < 8; s++) {
      int csw = (s * 4 + quad) ^ (lq & 7);  // swizzled chunk within key row
#pragma unroll
      for (int tt = 0; tt < 2; tt++) {
        f16x8 kf = *(const f16x8*)&sKb[((tt * 16 + lq) * 32 + csw) * 8];
        st[0][tt] = __builtin_amdgcn_mfma_f32_16x16x32_f16(qfrag[0][s], kf, st[0][tt], 0, 0, 0);
        st[1][tt] = __builtin_amdgcn_mfma_f32_16x16x32_f16(qfrag[1][s], kf, st[1][tt], 0, 0, 0);
      }
    }
    // P = exp(s - 32) -> bf16 (no max, no rescale; offset cancels in O/l)
#pragma unroll
    for (int qt = 0; qt < 2; qt++)
#pragma unroll
      for (int tt = 0; tt < 2; tt++)
#pragma unroll
        for (int r = 0; r < 4; r++) {
          float p = __expf(st[qt][tt][r] - Coff);
          sPw[(qt * 16 + quad * 4 + r) * 40 + tt * 16 + lq] = f2bf(p);
        }
    // O += P @ V'; each vf feeds 2 MFMAs; ones-column -> l
    bs16x8 pf0 = *(const bs16x8*)&sPw[lq * 40 + quad * 8];
    bs16x8 pf1 = *(const bs16x8*)&sPw[(16 + lq) * 40 + quad * 8];
    const int vsw = quad ^ ((lq >> 1) & 3);  // swizzled chunk within d row
#pragma unroll
    for (int c = 0; c < 16; c++) {
      bs16x8 vf = *(const bs16x8*)&sVb[((c * 16 + lq) * 4 + vsw) * 8];
      O[0][c] = __builtin_amdgcn_mfma_f32_16x16x32_bf16(pf0, vf, O[0][c], 0, 0, 0);
      O[1][c] = __builtin_amdgcn_mfma_f32_16x16x32_bf16(pf1, vf, O[1][c], 0, 0, 0);
    }
    O[0][16] = __builtin_amdgcn_mfma_f32_16x16x32_bf16(pf0, onesb, O[0][16], 0, 0, 0);
    O[1][16] = __builtin_amdgcn_mfma_f32_16x16x32_bf16(pf1, onesb, O[1][16], 0, 0, 0);
  }
  // epilogue: out = relu(O/l + bo), fp32
#pragma unroll
  for (int qt = 0; qt < 2; qt++) {
    float inv[4];
#pragma unroll
    for (int r = 0; r < 4; r++) inv[r] = 1.f / O[qt][16][r];
    const size_t base = ((size_t)b * Nn + n0 + w * 32 + qt * 16 + quad * 4) * Dn;
#pragma unroll
    for (int c = 0; c < 16; c++) {
      int col = c * 16 + lq;
#pragma unroll
      for (int r = 0; r < 4; r++) {
        float v = O[qt][c][r] * inv[r] + bo_r[c];
        out[base + (size_t)r * Dn + col] = v > 0.f ? v : 0.f;
      }
    }
  }
}

// ---------------------------------------------------------------- launch
extern "C" void kernel_launch(void* const* d_in, const int* in_sizes, int n_in,
                              void* d_out, int out_size, void* d_ws, size_t ws_size,
                              hipStream_t stream) {
  const float* inp = (const float*)d_in[0];
  const float* Wq  = (const float*)d_in[1];
  const float* bq  = (const float*)d_in[2];
  const float* Wk  = (const float*)d_in[3];
  const float* bk  = (const float*)d_in[4];
  const float* Wo  = (const float*)d_in[5];
  const float* bo  = (const float*)d_in[6];

  unsigned short* ws16 = (unsigned short*)d_ws;
  const size_t SZH = (size_t)Bn * Nn * Dn;  // 8.39M halves (16.8 MB)
  unsigned short* Qf = ws16;                // fp16 [b][n][d]
  unsigned short* Kf = ws16 + SZH;          // fp16 [b][n][d]
  unsigned short* Vp = ws16 + 2 * SZH;      // fp16 [b][n][d]  (inp@Wo)
  unsigned short* VT = ws16 + 3 * SZH;      // bf16 [b][d][n]
  unsigned short* WT = ws16 + 4 * SZH;      // 3 x 65536 fp16

  prep_w<<<768, 256, 0, stream>>>(Wq, Wk, Wo, WT);
  gemm_kernel<<<dim3(512, 3), 256, 0, stream>>>(inp, WT, bq, bk, Qf, Kf, Vp);
  transpose_h<<<dim3(32, 4, 16), 256, 0, stream>>>(Vp, VT);
  attn_kernel<<<256, 256, 0, stream>>>(Qf, Kf, VT, bo, (float*)d_out);
}

// Round 6
// 226.716 us; speedup vs baseline: 2.6738x; 1.1320x over previous
//
#include <hip/hip_runtime.h>

// GraphReasonLayer: out = relu( (softmax(QK^T) @ inp) @ Wo + bo ),
//   Q = inp@Wq+bq, K = inp@Wk+bk.  B=16, N=2048, D=256, fp32 in/out.
// R6: split-K attention. R5 core (exp(s-32) no-rescale softmax, Wo folded
// into V', global_load_lds dbuf staging, XOR source swizzle) but grid 512 =
// 256 q-blocks x 2 key-halves -> 2 blocks/CU (LDS 2x75776 fits 160K, VGPR
// 168<=256) = 2 waves/SIMD, hiding the scores->exp->PV serial chain that
// left R5 60% idle at 1 wave/SIMD. Partials: kh0 -> d_out, kh1 -> ws;
// combine kernel: out = relu((O0+O1)/(l0+l1) + bo). V' transpose fused
// into gemm epilogue (transpose_h deleted).

#define DEVI __device__ __forceinline__

using f16x8  = __attribute__((ext_vector_type(8))) _Float16;
using bs16x8 = __attribute__((ext_vector_type(8))) short;  // bf16 bits
using f32x4  = __attribute__((ext_vector_type(4))) float;
using u16x4  = __attribute__((ext_vector_type(4))) unsigned short;
using u16x8  = __attribute__((ext_vector_type(8))) unsigned short;

constexpr int Bn = 16, Nn = 2048, Dn = 256;
constexpr float Coff = 32.0f;  // fixed softmax offset; cancels in O/l

DEVI unsigned short f2h(float x) {
  return __builtin_bit_cast(unsigned short, (_Float16)x);
}
DEVI unsigned short f2bf(float x) {  // RNE float->bf16
  union { float f; unsigned u; } v; v.f = x;
  unsigned r = v.u + 0x7fff + ((v.u >> 16) & 1);
  return (unsigned short)(r >> 16);
}

// async global->LDS, 16B per lane; LDS dest = wave-uniform base + lane*16
DEVI void gll16(const void* g, void* l) {
  __builtin_amdgcn_global_load_lds(
      (const __attribute__((address_space(1))) unsigned int*)g,
      (__attribute__((address_space(3))) unsigned int*)l, 16, 0, 0);
}

// ---------------------------------------------------------------- prep_w
// WT[mat][n][k] = W[k][n] as fp16 (0=Wq, 1=Wk, 2=Wo).
__global__ __launch_bounds__(256) void prep_w(
    const float* __restrict__ Wq, const float* __restrict__ Wk,
    const float* __restrict__ Wo, unsigned short* __restrict__ WT) {
  const int mat = blockIdx.x >> 8, n = blockIdx.x & 255, k = threadIdx.x;
  const float* src = mat == 0 ? Wq : (mat == 1 ? Wk : Wo);
  WT[(size_t)mat * 65536 + n * 256 + k] = f2h(src[k * 256 + n]);
}

// ---------------------------------------------------------------- GEMM
// s=0: Qf = inp@Wq+bq (fp16 [b][n][d]); s=1: Kf = inp@Wk+bk (fp16);
// s=2: VT = (inp@Wo)^T (bf16 [b][d][n] — transpose fused in epilogue).
__global__ __launch_bounds__(256, 4) void gemm_kernel(
    const float* __restrict__ A, const unsigned short* __restrict__ WTbase,
    const float* __restrict__ bq, const float* __restrict__ bk,
    unsigned short* __restrict__ Qf, unsigned short* __restrict__ Kf,
    unsigned short* __restrict__ VTo) {
  __shared__ __align__(16) unsigned short sA[64 * 40];
  __shared__ __align__(16) unsigned short sW[256 * 40];
  const int t = threadIdx.x, w = t >> 6, l = t & 63;
  const int lq = l & 15, quad = l >> 4;
  const int m0 = blockIdx.x * 64, s = blockIdx.y;
  const unsigned short* WT = WTbase + (size_t)s * 65536;

  f32x4 acc[16];
#pragma unroll
  for (int c = 0; c < 16; c++) acc[c] = f32x4{0.f, 0.f, 0.f, 0.f};

  for (int kc = 0; kc < 8; kc++) {
    __syncthreads();
    {  // stage A 64x32 fp32->fp16
      int r = t >> 2, k8 = (t & 3) * 8;
      const float* Ap = A + (size_t)(m0 + r) * Dn + kc * 32 + k8;
      float4 v0 = *(const float4*)Ap, v1 = *(const float4*)(Ap + 4);
      u16x8 h;
      h[0] = f2h(v0.x); h[1] = f2h(v0.y); h[2] = f2h(v0.z); h[3] = f2h(v0.w);
      h[4] = f2h(v1.x); h[5] = f2h(v1.y); h[6] = f2h(v1.z); h[7] = f2h(v1.w);
      *(u16x8*)&sA[r * 40 + k8] = h;
    }
#pragma unroll
    for (int j = 0; j < 4; j++) {  // stage W chunk [256 n][32 k]
      int idx = j * 256 + t, n = idx >> 2, k8 = (idx & 3) * 8;
      *(uint4*)&sW[n * 40 + k8] = *(const uint4*)(WT + (size_t)n * 256 + kc * 32 + k8);
    }
    __syncthreads();
    f16x8 a = *(const f16x8*)&sA[(w * 16 + lq) * 40 + quad * 8];
#pragma unroll
    for (int c = 0; c < 16; c++) {
      f16x8 bf = *(const f16x8*)&sW[(c * 16 + lq) * 40 + quad * 8];
      acc[c] = __builtin_amdgcn_mfma_f32_16x16x32_f16(a, bf, acc[c], 0, 0, 0);
    }
  }
  const int row_l = w * 16 + quad * 4;
  if (s == 2) {  // fused transpose: VT[b][d][n] bf16, b64 stores (4 n's)
    const int bb = m0 >> 11, nloc = (m0 & 2047) + row_l;
#pragma unroll
    for (int c = 0; c < 16; c++) {
      int col = c * 16 + lq;
      u16x4 o;
#pragma unroll
      for (int r = 0; r < 4; r++) o[r] = f2bf(acc[c][r]);
      *(u16x4*)(VTo + ((size_t)bb * Dn + col) * Nn + nloc) = o;
    }
  } else {
    const float* bias = s == 0 ? bq : bk;
    unsigned short* outH = s == 0 ? Qf : Kf;
#pragma unroll
    for (int c = 0; c < 16; c++) {
      int col = c * 16 + lq;
      float bs = bias[col];
#pragma unroll
      for (int r = 0; r < 4; r++)
        outH[(size_t)(m0 + row_l + r) * Dn + col] = f2h(acc[c][r] + bs);
    }
  }
}

// ---------------------------------------------------------------- attention
// 256 thr = 4 waves x 32 q = 128 q/block; grid 512 = 256 qblocks x 2 khalves
// (2 blocks/CU, 2 waves/SIMD). Each block: 32 key-chunks of 32. Partial
// O (unnormalized) and l written out; combine kernel finishes.
__global__ __launch_bounds__(256, 2) void attn_kernel(
    const unsigned short* __restrict__ Qf, const unsigned short* __restrict__ Kf,
    const unsigned short* __restrict__ VT,
    float* __restrict__ Op0, float* __restrict__ Op1, float* __restrict__ lp) {
  __shared__ __align__(16) unsigned short sK[2][8192];  // 2 x 16 KB
  __shared__ __align__(16) unsigned short sV[2][8192];  // 2 x 16 KB
  __shared__ __align__(16) unsigned short sP[4][1280];  // per-wave, 32 x 40
  const int t = threadIdx.x, w = t >> 6, l = t & 63;
  const int lq = l & 15, quad = l >> 4;
  // decode: id = xcd + 8*(kh + 2*(qb + 16*bhi));  batches b,b+8 on XCD id&7
  const int id = blockIdx.x, xcd = id & 7, r2 = id >> 3;
  const int kh = r2 & 1, qb = (r2 >> 1) & 15, bhi = r2 >> 5;
  const int b = xcd | (bhi << 3), n0 = qb * 128;
  unsigned short* sPw = sP[w];

  const unsigned short* kg = Kf + ((size_t)b * Nn + kh * 1024) * Dn;
  const unsigned short* vg = VT + (size_t)b * Dn * Nn + kh * 1024;

  // Q fragments: 2 q-tiles x 8 k-steps (A-layout m=lq, k=quad*8+j)
  f16x8 qfrag[2][8];
#pragma unroll
  for (int qt = 0; qt < 2; qt++) {
    const unsigned short* qp =
        Qf + ((size_t)b * Nn + n0 + w * 32 + qt * 16 + lq) * Dn + quad * 8;
#pragma unroll
    for (int s = 0; s < 8; s++) qfrag[qt][s] = *(const f16x8*)(qp + s * 32);
  }
  bs16x8 onesb;
#pragma unroll
  for (int i = 0; i < 8; i++) onesb[i] = (short)0x3F80;  // bf16 1.0

  f32x4 O[2][17];  // [qtile][16 d-tiles + l]; pure MFMA sinks
#pragma unroll
  for (int qt = 0; qt < 2; qt++)
#pragma unroll
    for (int c = 0; c < 17; c++) O[qt][c] = f32x4{0.f, 0.f, 0.f, 0.f};

  // ---- async stage of one 32-key chunk (XOR source swizzle, 8 gll16/thr)
  auto stage = [&](int buf, int m0) {
#pragma unroll
    for (int j = 0; j < 4; j++) {           // K: 1024 16B-chunks
      int g = w * 4 + j;                    // wave-uniform instr index
      int phys = g * 64 + l;
      int key = phys >> 5;
      int c = (phys & 31) ^ (key & 7);
      gll16(kg + (size_t)(m0 + key) * Dn + c * 8, &sK[buf][g * 512]);
    }
#pragma unroll
    for (int j = 0; j < 4; j++) {           // V: 1024 16B-chunks
      int g = w * 4 + j;
      int phys = g * 64 + l;
      int d = phys >> 2;
      int c = (phys & 3) ^ ((d >> 1) & 3);
      gll16(vg + (size_t)d * Nn + m0 + c * 8, &sV[buf][g * 512]);
    }
  };

  stage(0, 0);  // prologue

  for (int mc = 0; mc < 32; mc++) {
    const int buf = mc & 1;
    __syncthreads();  // drains vmcnt -> buf ready; all waves done with buf^1
    if (mc < 31) stage(buf ^ 1, (mc + 1) * 32);
    const unsigned short* sKb = sK[buf];
    const unsigned short* sVb = sV[buf];

    // scores: 32 q x 32 keys; each kf feeds 2 MFMAs
    f32x4 st[2][2];
#pragma unroll
    for (int qt = 0; qt < 2; qt++)
#pragma unroll
      for (int tt = 0; tt < 2; tt++) st[qt][tt] = f32x4{0.f, 0.f, 0.f, 0.f};
#pragma unroll
    for (int s = 0; s < 8; s++) {
      int csw = (s * 4 + quad) ^ (lq & 7);
#pragma unroll
      for (int tt = 0; tt < 2; tt++) {
        f16x8 kf = *(const f16x8*)&sKb[((tt * 16 + lq) * 32 + csw) * 8];
        st[0][tt] = __builtin_amdgcn_mfma_f32_16x16x32_f16(qfrag[0][s], kf, st[0][tt], 0, 0, 0);
        st[1][tt] = __builtin_amdgcn_mfma_f32_16x16x32_f16(qfrag[1][s], kf, st[1][tt], 0, 0, 0);
      }
    }
    // P = exp(s - 32) -> bf16 (no max, no rescale; offset cancels in O/l)
#pragma unroll
    for (int qt = 0; qt < 2; qt++)
#pragma unroll
      for (int tt = 0; tt < 2; tt++)
#pragma unroll
        for (int r = 0; r < 4; r++) {
          float p = __expf(st[qt][tt][r] - Coff);
          sPw[(qt * 16 + quad * 4 + r) * 40 + tt * 16 + lq] = f2bf(p);
        }
    // O += P @ V'; each vf feeds 2 MFMAs; ones-column -> l
    bs16x8 pf0 = *(const bs16x8*)&sPw[lq * 40 + quad * 8];
    bs16x8 pf1 = *(const bs16x8*)&sPw[(16 + lq) * 40 + quad * 8];
    const int vsw = quad ^ ((lq >> 1) & 3);
#pragma unroll
    for (int c = 0; c < 16; c++) {
      bs16x8 vf = *(const bs16x8*)&sVb[((c * 16 + lq) * 4 + vsw) * 8];
      O[0][c] = __builtin_amdgcn_mfma_f32_16x16x32_bf16(pf0, vf, O[0][c], 0, 0, 0);
      O[1][c] = __builtin_amdgcn_mfma_f32_16x16x32_bf16(pf1, vf, O[1][c], 0, 0, 0);
    }
    O[0][16] = __builtin_amdgcn_mfma_f32_16x16x32_bf16(pf0, onesb, O[0][16], 0, 0, 0);
    O[1][16] = __builtin_amdgcn_mfma_f32_16x16x32_bf16(pf1, onesb, O[1][16], 0, 0, 0);
  }
  // epilogue: write raw partial O and l (normalization in combine)
  float* Op = kh ? Op1 : Op0;
#pragma unroll
  for (int qt = 0; qt < 2; qt++) {
    const int qrow = n0 + w * 32 + qt * 16 + quad * 4;
    const size_t base = ((size_t)b * Nn + qrow) * Dn;
#pragma unroll
    for (int c = 0; c < 16; c++) {
      int col = c * 16 + lq;
#pragma unroll
      for (int r = 0; r < 4; r++)
        Op[base + (size_t)r * Dn + col] = O[qt][c][r];
    }
    if (lq == 0) {
#pragma unroll
      for (int r = 0; r < 4; r++)
        lp[(size_t)kh * (Bn * Nn) + (size_t)b * Nn + qrow + r] = O[qt][16][r];
    }
  }
}

// ---------------------------------------------------------------- combine
// out = relu((O0 + O1) / (l0 + l1) + bo); O0 lives in d_out (in-place).
__global__ __launch_bounds__(256) void combine_kernel(
    const float* __restrict__ Op1, const float* __restrict__ lp,
    const float* __restrict__ bo, float* __restrict__ out) {
  const size_t g = (size_t)blockIdx.x * 256 + threadIdx.x;  // float4 idx
  const size_t row = g >> 6;
  const int d4 = (int)(g & 63) << 2;
  const size_t off = row * Dn + d4;
  float4 a = *(const float4*)(out + off);
  float4 c = *(const float4*)(Op1 + off);
  float inv = 1.f / (lp[row] + lp[(size_t)Bn * Nn + row]);
  float4 bb = *(const float4*)(bo + d4);
  float4 r;
  r.x = fmaxf((a.x + c.x) * inv + bb.x, 0.f);
  r.y = fmaxf((a.y + c.y) * inv + bb.y, 0.f);
  r.z = fmaxf((a.z + c.z) * inv + bb.z, 0.f);
  r.w = fmaxf((a.w + c.w) * inv + bb.w, 0.f);
  *(float4*)(out + off) = r;
}

// ---------------------------------------------------------------- launch
extern "C" void kernel_launch(void* const* d_in, const int* in_sizes, int n_in,
                              void* d_out, int out_size, void* d_ws, size_t ws_size,
                              hipStream_t stream) {
  const float* inp = (const float*)d_in[0];
  const float* Wq  = (const float*)d_in[1];
  const float* bq  = (const float*)d_in[2];
  const float* Wk  = (const float*)d_in[3];
  const float* bk  = (const float*)d_in[4];
  const float* Wo  = (const float*)d_in[5];
  const float* bo  = (const float*)d_in[6];
  float* out = (float*)d_out;

  unsigned short* ws16 = (unsigned short*)d_ws;
  const size_t SZH = (size_t)Bn * Nn * Dn;      // 8.39M halves (16.8 MB)
  unsigned short* Qf  = ws16;                   // fp16 [b][n][d]
  unsigned short* Kf  = ws16 + SZH;             // fp16 [b][n][d]
  unsigned short* VT  = ws16 + 2 * SZH;         // bf16 [b][d][n]
  float*          Op1 = (float*)(ws16 + 3 * SZH);       // fp32, 33.5 MB
  float*          lp  = (float*)(ws16 + 5 * SZH);       // fp32 [2][B*N]
  unsigned short* WT  = ws16 + 5 * SZH + 2 * (Bn * Nn); // 3 x 65536 fp16
  // total ws use: 5*16.8 + 0.26 + 0.39 MB ~= 84.6 MB

  prep_w<<<768, 256, 0, stream>>>(Wq, Wk, Wo, WT);
  gemm_kernel<<<dim3(512, 3), 256, 0, stream>>>(inp, WT, bq, bk, Qf, Kf, VT);
  attn_kernel<<<512, 256, 0, stream>>>(Qf, Kf, VT, out, Op1, lp);
  combine_kernel<<<8192, 256, 0, stream>>>(Op1, lp, bo, out);
}